// Round 4
// baseline (383.219 us; speedup 1.0000x reference)
//
#include <hip/hip_runtime.h>

#define NEG_SLOPE 0.2f
#define CHUNK 2048     // scan chunk (nodes)
#define CHUNKP 2048    // partition chunk (edges)
#define NRANGE 8       // dst ranges; blockIdx.x (fastest) -> XCD round-robin

__device__ __forceinline__ ushort f2bf(float f) {
    union { float f; unsigned u; } c; c.f = f;
    unsigned u = c.u;
    return (ushort)((u + 0x7fffu + ((u >> 16) & 1u)) >> 16);   // RNE
}

// ---------------- fused prep: zero counters + out[:, :128]=x + xbf=bf16(x) + scores
__global__ __launch_bounds__(256) void prep_kernel(
    const float* __restrict__ x, const float* __restrict__ wu,
    const float* __restrict__ bu, const float* __restrict__ wv,
    float* __restrict__ out, ushort* __restrict__ xbf,
    float* __restrict__ su, float* __restrict__ sv,
    int* __restrict__ zbase, int nzero, int N, int convBlocks)
{
    __shared__ float wlds[32 * 129];
    int tid = threadIdx.x;
    int bid = blockIdx.x;
    if (bid < convBlocks) {
        int gid = bid * 256 + tid;
        if (gid < nzero) zbase[gid] = 0;           // cnt + gcursor zero-init
        int i = gid;                                // one float4 per thread
        if (i < N * 32) {
            float4 v = ((const float4*)x)[i];
            int n = i >> 5, q = i & 31;
            ((float4*)out)[(size_t)n * 96 + q] = v;
            ushort4 b;
            b.x = f2bf(v.x); b.y = f2bf(v.y); b.z = f2bf(v.z); b.w = f2bf(v.w);
            *(ushort4*)(xbf + (size_t)i * 4) = b;
        }
        return;
    }
    // ---- scores path
    for (int i = tid; i < 4096; i += 256) {
        int o = i >> 7, k = i & 127;
        wlds[o * 129 + k] = (o < 16) ? wu[i] : wv[i - 2048];
    }
    __syncthreads();
    int o = tid & 15;
    int n = (bid - convBlocks) * 16 + (tid >> 4);
    if (n >= N) return;
    const float4* xr4 = (const float4*)(x + (size_t)n * 128);
    const float* wur = wlds + o * 129;
    const float* wvr = wlds + (16 + o) * 129;
    float au = 0.f, av = 0.f;
#pragma unroll
    for (int kk = 0; kk < 32; ++kk) {
        float4 xv = xr4[kk];
        int k = kk * 4;
        au = fmaf(xv.x, wur[k],     au);  av = fmaf(xv.x, wvr[k],     av);
        au = fmaf(xv.y, wur[k + 1], au);  av = fmaf(xv.y, wvr[k + 1], av);
        au = fmaf(xv.z, wur[k + 2], au);  av = fmaf(xv.z, wvr[k + 2], av);
        au = fmaf(xv.w, wur[k + 3], au);  av = fmaf(xv.w, wvr[k + 3], av);
    }
    su[n * 16 + o] = au + bu[o];
    sv[n * 16 + o] = av;
}

// ---------------- partition: read edges ONCE, pack (dst<<16)|src into per-range segments
__global__ __launch_bounds__(256) void part_kernel(
    const int* __restrict__ s0, const int* __restrict__ d0,
    const int* __restrict__ s1, const int* __restrict__ d1,
    int* __restrict__ gcur, unsigned* __restrict__ pairs,
    int E, int shift, int cap)
{
    int t = blockIdx.y;
    const int* ss = t ? s1 : s0;
    const int* dd = t ? d1 : d0;
    int beg = blockIdx.x * CHUNKP, end = min(E, beg + CHUNKP);
    __shared__ int lcnt[NRANGE], gb[NRANGE], lrun[NRANGE];
    if (threadIdx.x < NRANGE) lcnt[threadIdx.x] = 0;
    __syncthreads();
    for (int e = beg + (int)threadIdx.x; e < end; e += 256)
        atomicAdd(&lcnt[dd[e] >> shift], 1);
    __syncthreads();
    if (threadIdx.x < NRANGE) {
        gb[threadIdx.x] = atomicAdd(&gcur[t * NRANGE + threadIdx.x], lcnt[threadIdx.x]);
        lrun[threadIdx.x] = 0;
    }
    __syncthreads();
    unsigned* pt = pairs + (size_t)t * NRANGE * cap;
    for (int e = beg + (int)threadIdx.x; e < end; e += 256) {
        int dst = dd[e], src = ss[e];
        int r = dst >> shift;
        int pos = atomicAdd(&lrun[r], 1);
        pt[(size_t)r * cap + gb[r] + pos] = ((unsigned)dst << 16) | (unsigned)src;
    }
}

// ---------------- histogram from partitioned pairs (range-local cnt window)
__global__ __launch_bounds__(256) void hist2_kernel(
    const unsigned* __restrict__ pairs, const int* __restrict__ gcur,
    int* __restrict__ cnt, int N, int cap)
{
    int r = blockIdx.x, c = blockIdx.y, t = blockIdx.z;
    int m = gcur[t * NRANGE + r];
    const unsigned* p = pairs + ((size_t)t * NRANGE + r) * cap;
    int chunk = (m + gridDim.y - 1) / gridDim.y;
    int beg = c * chunk, end = min(m, beg + chunk);
    int* ct = cnt + (size_t)t * N;
    for (int i = beg + (int)threadIdx.x; i < end; i += 256)
        atomicAdd(ct + (p[i] >> 16), 1);
}

// ---------------- scan A: per-chunk totals
__global__ __launch_bounds__(256) void scanA_kernel(
    const int* __restrict__ cnt, int* __restrict__ partials, int N)
{
    int t = blockIdx.y, c = blockIdx.x, tid = threadIdx.x;
    const int* ct = cnt + (size_t)t * N;
    int base = c * CHUNK + tid * 8;
    int s = 0;
#pragma unroll
    for (int j = 0; j < 8; ++j) { int i = base + j; if (i < N) s += ct[i]; }
#pragma unroll
    for (int d = 1; d < 64; d <<= 1) s += __shfl_xor(s, d);
    __shared__ int wsum[4];
    if ((tid & 63) == 0) wsum[tid >> 6] = s;
    __syncthreads();
    if (tid == 0) partials[t * 32 + c] = wsum[0] + wsum[1] + wsum[2] + wsum[3];
}

// ---------------- scan C (scanB folded in): final offsets + cursor init
__global__ __launch_bounds__(256) void scanC_kernel(
    const int* __restrict__ cnt, const int* __restrict__ partials,
    int* __restrict__ off, int* __restrict__ cursor, int N, int nch)
{
    int t = blockIdx.y, c = blockIdx.x, tid = threadIdx.x;
    __shared__ int sb, stot;
    if (tid < 32) {                        // redundant 32-lane scan of chunk totals
        int v = (tid < nch) ? partials[t * 32 + tid] : 0;
        int incl = v;
#pragma unroll
        for (int d = 1; d < 32; d <<= 1) {
            int o = __shfl(incl, tid - d);
            if (tid >= d) incl += o;
        }
        if (tid == c) sb = incl - v;
        if (tid == nch - 1) stot = incl;
    }
    const int* ct = cnt + (size_t)t * N;
    int base = c * CHUNK + tid * 8;
    int v[8], tot = 0;
#pragma unroll
    for (int j = 0; j < 8; ++j) { int i = base + j; v[j] = (i < N) ? ct[i] : 0; tot += v[j]; }
    __shared__ int lds[256];
    lds[tid] = tot;
    __syncthreads();
    int incl = tot;
    for (int d = 1; d < 256; d <<= 1) {
        int add = (tid >= d) ? lds[tid - d] : 0;
        __syncthreads();
        incl += add;
        lds[tid] = incl;
        __syncthreads();
    }
    int run = incl - tot + sb;
#pragma unroll
    for (int j = 0; j < 8; ++j) {
        int i = base + j;
        if (i < N) { off[(size_t)t * (N + 1) + i] = run; cursor[(size_t)t * N + i] = run; }
        run += v[j];
    }
    if (c == 0 && tid == 0) off[(size_t)t * (N + 1) + N] = stot;
}

// ---------------- fill bucket (ushort src) from partitioned pairs, range-local
__global__ __launch_bounds__(256) void fill2_kernel(
    const unsigned* __restrict__ pairs, const int* __restrict__ gcur,
    int* __restrict__ cursor, ushort* __restrict__ bucket, int N, int E, int cap)
{
    int r = blockIdx.x, c = blockIdx.y, t = blockIdx.z;
    int m = gcur[t * NRANGE + r];
    const unsigned* p = pairs + ((size_t)t * NRANGE + r) * cap;
    int chunk = (m + gridDim.y - 1) / gridDim.y;
    int beg = c * chunk, end = min(m, beg + chunk);
    int* cur = cursor + (size_t)t * N;
    ushort* bkt = bucket + (size_t)t * E;
    for (int i = beg + (int)threadIdx.x; i < end; i += 256) {
        unsigned v = p[i];
        int dst = v >> 16;
        int pos = atomicAdd(cur + dst, 1);
        bkt[pos] = (ushort)(v & 0xffffu);
    }
}

// ---------------- single-pass softmax+aggregate: one wave per (node, t)
__global__ __launch_bounds__(256) void agg_kernel(
    const ushort* __restrict__ xbf, const float* __restrict__ su,
    const float* __restrict__ sv, const int* __restrict__ off,
    const ushort* __restrict__ bucket, float* __restrict__ out, int N, int E)
{
    __shared__ __align__(16) float evals[4][512];
    int t = blockIdx.y;
    int wid = threadIdx.x >> 6;
    int lane = threadIdx.x & 63;
    int n = blockIdx.x * 4 + wid;
    if (n >= N) return;
    const int* offt = off + (size_t)t * (N + 1);
    const ushort* bkt = bucket + (size_t)t * E;
    int beg = offt[n], end = offt[n + 1];
    int h = lane & 7;            // e-phase head class
    int e8 = lane >> 3;          // e-phase edge stripe
    float vh = sv[n * 16 + t * 8 + h];
    float* ev = evals[wid];

    int hf = lane >> 5;          // acc-phase: which of 2 edges
    int q = lane & 31;
    int j0 = q * 4;              // acc-phase: 4 output elems per lane
    int hbase = (q & 1) * 4;     // heads for j0..j0+3 are hbase..hbase+3
    float acc0 = 0.f, acc1 = 0.f, acc2 = 0.f, acc3 = 0.f;
    float l = 0.f;

    for (int cbeg = beg; cbeg < end; cbeg += 64) {
        int cnt = min(end - cbeg, 64);
        int gmax = (cnt + 7) >> 3;
        // e-phase: 8 edges x 8 heads in parallel per iteration
        for (int g = 0; g < gmax; ++g) {
            int e = g * 8 + e8;
            bool valid = e < cnt;
            int srcv = 0;
            if (valid) srcv = bkt[cbeg + e];
            float s = su[srcv * 16 + t * 8 + h] + vh;
            s = (s >= 0.f) ? s : NEG_SLOPE * s;
            float eval = valid ? __expf(s) : 0.f;
            l += eval;
            ev[e * 8 + h] = eval;
        }
        // acc-phase: 2 edges per iteration (half-wave each, float4/lane)
        int pairs2 = (cnt + 1) >> 1;
        for (int i2 = 0; i2 < pairs2; ++i2) {
            int eidx = i2 * 2 + hf;
            int srcv = 0;
            if (eidx < cnt) srcv = bkt[cbeg + eidx];
            float4 p4 = *(const float4*)(ev + eidx * 8 + hbase);
            uint2 u = *(const uint2*)(xbf + (size_t)srcv * 128 + j0);
            float x0 = __uint_as_float(u.x << 16);
            float x1 = __uint_as_float(u.x & 0xffff0000u);
            float x2 = __uint_as_float(u.y << 16);
            float x3 = __uint_as_float(u.y & 0xffff0000u);
            acc0 = fmaf(x0, p4.x, acc0);
            acc1 = fmaf(x1, p4.y, acc1);
            acc2 = fmaf(x2, p4.z, acc2);
            acc3 = fmaf(x3, p4.w, acc3);
        }
    }
    // reduce exp-sum across stripes (keeps head class h)
    l += __shfl_xor(l, 8);
    l += __shfl_xor(l, 16);
    l += __shfl_xor(l, 32);
    float invl = (l > 0.f) ? (1.f / l) : 0.f;
    // combine the two half-wave edge groups
    acc0 += __shfl_xor(acc0, 32);
    acc1 += __shfl_xor(acc1, 32);
    acc2 += __shfl_xor(acc2, 32);
    acc3 += __shfl_xor(acc3, 32);
    float i0 = __shfl(invl, hbase);
    float i1 = __shfl(invl, hbase + 1);
    float i2v = __shfl(invl, hbase + 2);
    float i3 = __shfl(invl, hbase + 3);
    if (hf == 0) {
        float4 r = make_float4(acc0 * i0, acc1 * i1, acc2 * i2v, acc3 * i3);
        *(float4*)(out + (size_t)n * 384 + 128 + (size_t)t * 128 + j0) = r;
    }
}

extern "C" void kernel_launch(void* const* d_in, const int* in_sizes, int n_in,
                              void* d_out, int out_size, void* d_ws, size_t ws_size,
                              hipStream_t stream)
{
    const float* x  = (const float*)d_in[0];
    const float* wu = (const float*)d_in[1];
    const float* bu = (const float*)d_in[2];
    const float* wv = (const float*)d_in[3];
    const int* s0 = (const int*)d_in[4];
    const int* d0 = (const int*)d_in[5];
    const int* s1 = (const int*)d_in[6];
    const int* d1 = (const int*)d_in[7];
    float* out = (float*)d_out;
    int N = in_sizes[0] / 128;
    int E = in_sizes[4];
    int nch = (N + CHUNK - 1) / CHUNK;        // 25 for N=50000 (<=32)

    int shift = 0;                            // dst>>shift in [0, NRANGE)
    while (((N - 1) >> shift) >= NRANGE) ++shift;   // N=50000 -> 13
    long long mean = ((long long)1 << shift) * E / N;
    int cap = (int)(mean + mean / 4 + 4096);  // ~168K: mean 131K, sigma ~330

    char* ws = (char*)d_ws;
    size_t o = 0;
    auto alloc = [&](size_t bytes) -> void* {
        void* p = ws + o;
        o = (o + bytes + 255) & ~(size_t)255;
        return p;
    };
    float* su       = (float*)alloc((size_t)N * 16 * 4);
    float* sv       = (float*)alloc((size_t)N * 16 * 4);
    int* cnt        = (int*)alloc(((size_t)2 * N + 16) * 4);  // cnt + gcur contiguous
    int* gcur       = cnt + (size_t)2 * N;
    int* cursor     = (int*)alloc((size_t)2 * N * 4);
    int* off        = (int*)alloc((size_t)2 * (N + 1) * 4);
    int* partials   = (int*)alloc(64 * 4);
    unsigned* pairs = (unsigned*)alloc((size_t)2 * NRANGE * cap * 4);
    ushort* bucket  = (ushort*)alloc((size_t)2 * E * 2);
    ushort* xbf     = (ushort*)alloc((size_t)N * 128 * 2);

    int convBlocks = (N * 32 + 255) / 256;
    int scoreBlocks = (N + 15) / 16;
    prep_kernel<<<convBlocks + scoreBlocks, 256, 0, stream>>>(
        x, wu, bu, wv, out, xbf, su, sv, cnt, 2 * N + 16, N, convBlocks);
    part_kernel<<<dim3((E + CHUNKP - 1) / CHUNKP, 2), 256, 0, stream>>>(
        s0, d0, s1, d1, gcur, pairs, E, shift, cap);
    hist2_kernel<<<dim3(NRANGE, 16, 2), 256, 0, stream>>>(pairs, gcur, cnt, N, cap);
    scanA_kernel<<<dim3(nch, 2), 256, 0, stream>>>(cnt, partials, N);
    scanC_kernel<<<dim3(nch, 2), 256, 0, stream>>>(cnt, partials, off, cursor, N, nch);
    fill2_kernel<<<dim3(NRANGE, 16, 2), 256, 0, stream>>>(
        pairs, gcur, cursor, bucket, N, E, cap);
    agg_kernel<<<dim3((N + 3) / 4, 2), 256, 0, stream>>>(
        xbf, su, sv, off, bucket, out, N, E);
}

// Round 5
// 273.445 us; speedup vs baseline: 1.4015x; 1.4015x over previous
//
#include <hip/hip_runtime.h>

#define NEG_SLOPE 0.2f
#define CHUNKP 2048    // partition chunk (edges)
#define RSHIFT 11      // range width 2048 nodes -> 25 ranges for N=50000
#define RW     2048
#define MAXR   32

__device__ __forceinline__ ushort f2bf(float f) {
    union { float f; unsigned u; } c; c.f = f;
    unsigned u = c.u;
    return (ushort)((u + 0x7fffu + ((u >> 16) & 1u)) >> 16);   // RNE
}

// ---------------- mega: out[:, :128]=x + xbf=bf16(x) | scores | edge partition
// Three independent block roles fused into one dispatch (gcur pre-zeroed).
__global__ __launch_bounds__(256) void mega_kernel(
    const float* __restrict__ x, const float* __restrict__ wu,
    const float* __restrict__ bu, const float* __restrict__ wv,
    const int* __restrict__ s0, const int* __restrict__ d0,
    const int* __restrict__ s1, const int* __restrict__ d1,
    float* __restrict__ out, ushort* __restrict__ xbf,
    float* __restrict__ su, float* __restrict__ sv,
    int* __restrict__ gcur, unsigned* __restrict__ pairs,
    int N, int E, int nr, int cap, int convBlocks, int scoreBlocks, int ppset)
{
    __shared__ float wlds[32 * 129];
    __shared__ int lcnt[MAXR], gb[MAXR], lrun[MAXR];
    int tid = threadIdx.x;
    int bid = blockIdx.x;

    if (bid < convBlocks) {                 // ---- role A: copy + bf16 convert
        int i = bid * 256 + tid;
        if (i < N * 32) {
            float4 v = ((const float4*)x)[i];
            int n = i >> 5, q = i & 31;
            ((float4*)out)[(size_t)n * 96 + q] = v;
            ushort4 b;
            b.x = f2bf(v.x); b.y = f2bf(v.y); b.z = f2bf(v.z); b.w = f2bf(v.w);
            *(ushort4*)(xbf + (size_t)i * 4) = b;
        }
        return;
    }
    if (bid < convBlocks + scoreBlocks) {   // ---- role B: scores
        for (int i = tid; i < 4096; i += 256) {
            int o = i >> 7, k = i & 127;
            wlds[o * 129 + k] = (o < 16) ? wu[i] : wv[i - 2048];
        }
        __syncthreads();
        int o = tid & 15;
        int n = (bid - convBlocks) * 16 + (tid >> 4);
        if (n >= N) return;
        const float4* xr4 = (const float4*)(x + (size_t)n * 128);
        const float* wur = wlds + o * 129;
        const float* wvr = wlds + (16 + o) * 129;
        float au = 0.f, av = 0.f;
#pragma unroll
        for (int kk = 0; kk < 32; ++kk) {
            float4 xv = xr4[kk];
            int k = kk * 4;
            au = fmaf(xv.x, wur[k],     au);  av = fmaf(xv.x, wvr[k],     av);
            au = fmaf(xv.y, wur[k + 1], au);  av = fmaf(xv.y, wvr[k + 1], av);
            au = fmaf(xv.z, wur[k + 2], au);  av = fmaf(xv.z, wvr[k + 2], av);
            au = fmaf(xv.w, wur[k + 3], au);  av = fmaf(xv.w, wvr[k + 3], av);
        }
        su[n * 16 + o] = au + bu[o];
        sv[n * 16 + o] = av;
        return;
    }
    // ---- role C: partition edges into per-(set,range) segments, read-once
    int pb = bid - convBlocks - scoreBlocks;
    int t = pb / ppset, c = pb % ppset;
    const int* ss = t ? s1 : s0;
    const int* dd = t ? d1 : d0;
    int beg = c * CHUNKP, end = min(E, beg + CHUNKP);
    if (tid < nr) lcnt[tid] = 0;
    __syncthreads();
    for (int e = beg + tid; e < end; e += 256)
        atomicAdd(&lcnt[dd[e] >> RSHIFT], 1);
    __syncthreads();
    if (tid < nr) {
        gb[tid] = atomicAdd(&gcur[t * MAXR + tid], lcnt[tid]);
        lrun[tid] = 0;
    }
    __syncthreads();
    unsigned* pt = pairs + (size_t)t * nr * cap;
    for (int e = beg + tid; e < end; e += 256) {
        int dst = dd[e], src = ss[e];
        int r = dst >> RSHIFT;
        int pos = atomicAdd(&lrun[r], 1);
        pt[(size_t)r * cap + gb[r] + pos] = ((unsigned)dst << 16) | (unsigned)src;
    }
}

// ---------------- build: fused hist + scan + fill. One block per (range, set).
// LDS counting sort over the range's 2048 dst slots; bucket writes range-local.
__global__ __launch_bounds__(1024) void build_kernel(
    const unsigned* __restrict__ pairs, const int* __restrict__ gcur,
    int* __restrict__ off, ushort* __restrict__ bucket,
    int N, int E, int nr, int cap)
{
    __shared__ int hist[RW];
    __shared__ int lds[1024];
    int r = blockIdx.x, t = blockIdx.y, tid = threadIdx.x;
    int m = gcur[t * MAXR + r];
    // global CSR base for this range = edges in earlier ranges (dst-ordered)
    int base = 0;
    if (tid < 32) {
        int v = (tid < r) ? gcur[t * MAXR + tid] : 0;
#pragma unroll
        for (int d = 1; d < 32; d <<= 1) v += __shfl_xor(v, d);
        if (tid == 0) lds[0] = v;
    }
    hist[tid] = 0; hist[tid + 1024] = 0;
    __syncthreads();
    base = lds[0];
    __syncthreads();
    const unsigned* p = pairs + ((size_t)t * nr + r) * cap;
    // pass 1: histogram of in-range dst
    for (int i = tid; i < m; i += 1024)
        atomicAdd(&hist[(p[i] >> 16) & (RW - 1)], 1);
    __syncthreads();
    // prefix scan: each thread owns 2 slots
    int h0 = hist[2 * tid], h1 = hist[2 * tid + 1];
    int tot = h0 + h1;
    lds[tid] = tot;
    __syncthreads();
    int incl = tot;
    for (int d = 1; d < 1024; d <<= 1) {
        int add = (tid >= d) ? lds[tid - d] : 0;
        __syncthreads();
        incl += add;
        lds[tid] = incl;
        __syncthreads();
    }
    int e0 = incl - tot, e1 = incl - tot + h0;
    int lo = r << RSHIFT;
    int* offt = off + (size_t)t * (N + 1);
    if (lo + 2 * tid < N)     offt[lo + 2 * tid]     = base + e0;
    if (lo + 2 * tid + 1 < N) offt[lo + 2 * tid + 1] = base + e1;
    hist[2 * tid] = e0; hist[2 * tid + 1] = e1;      // becomes the cursor
    if (r == 0 && tid == 0) offt[N] = E;
    __syncthreads();
    // pass 2: scatter src into bucket at base + cursor
    ushort* bkt = bucket + (size_t)t * E + base;
    for (int i = tid; i < m; i += 1024) {
        unsigned v = p[i];
        int pos = atomicAdd(&hist[(v >> 16) & (RW - 1)], 1);
        bkt[pos] = (ushort)(v & 0xffffu);
    }
}

// ---------------- single-pass softmax+aggregate: one wave per (node, t)
__global__ __launch_bounds__(256) void agg_kernel(
    const ushort* __restrict__ xbf, const float* __restrict__ su,
    const float* __restrict__ sv, const int* __restrict__ off,
    const ushort* __restrict__ bucket, float* __restrict__ out, int N, int E)
{
    __shared__ __align__(16) float evals[4][512];
    int t = blockIdx.y;
    int wid = threadIdx.x >> 6;
    int lane = threadIdx.x & 63;
    int n = blockIdx.x * 4 + wid;
    if (n >= N) return;
    const int* offt = off + (size_t)t * (N + 1);
    const ushort* bkt = bucket + (size_t)t * E;
    int beg = offt[n], end = offt[n + 1];
    int h = lane & 7;            // e-phase head class
    int e8 = lane >> 3;          // e-phase edge stripe
    float vh = sv[n * 16 + t * 8 + h];
    float* ev = evals[wid];

    int hf = lane >> 5;          // acc-phase: which of 2 edges
    int q = lane & 31;
    int j0 = q * 4;              // acc-phase: 4 output elems per lane
    int hbase = (q & 1) * 4;     // heads for j0..j0+3 are hbase..hbase+3
    float acc0 = 0.f, acc1 = 0.f, acc2 = 0.f, acc3 = 0.f;
    float l = 0.f;

    for (int cbeg = beg; cbeg < end; cbeg += 64) {
        int cnt = min(end - cbeg, 64);
        int gmax = (cnt + 7) >> 3;
        for (int g = 0; g < gmax; ++g) {
            int e = g * 8 + e8;
            bool valid = e < cnt;
            int srcv = 0;
            if (valid) srcv = bkt[cbeg + e];
            float s = su[srcv * 16 + t * 8 + h] + vh;
            s = (s >= 0.f) ? s : NEG_SLOPE * s;
            float eval = valid ? __expf(s) : 0.f;
            l += eval;
            ev[e * 8 + h] = eval;
        }
        int pairs2 = (cnt + 1) >> 1;
        for (int i2 = 0; i2 < pairs2; ++i2) {
            int eidx = i2 * 2 + hf;
            int srcv = 0;
            if (eidx < cnt) srcv = bkt[cbeg + eidx];
            float4 p4 = *(const float4*)(ev + eidx * 8 + hbase);
            uint2 u = *(const uint2*)(xbf + (size_t)srcv * 128 + j0);
            float x0 = __uint_as_float(u.x << 16);
            float x1 = __uint_as_float(u.x & 0xffff0000u);
            float x2 = __uint_as_float(u.y << 16);
            float x3 = __uint_as_float(u.y & 0xffff0000u);
            acc0 = fmaf(x0, p4.x, acc0);
            acc1 = fmaf(x1, p4.y, acc1);
            acc2 = fmaf(x2, p4.z, acc2);
            acc3 = fmaf(x3, p4.w, acc3);
        }
    }
    l += __shfl_xor(l, 8);
    l += __shfl_xor(l, 16);
    l += __shfl_xor(l, 32);
    float invl = (l > 0.f) ? (1.f / l) : 0.f;
    acc0 += __shfl_xor(acc0, 32);
    acc1 += __shfl_xor(acc1, 32);
    acc2 += __shfl_xor(acc2, 32);
    acc3 += __shfl_xor(acc3, 32);
    float i0 = __shfl(invl, hbase);
    float i1 = __shfl(invl, hbase + 1);
    float i2v = __shfl(invl, hbase + 2);
    float i3 = __shfl(invl, hbase + 3);
    if (hf == 0) {
        float4 r = make_float4(acc0 * i0, acc1 * i1, acc2 * i2v, acc3 * i3);
        *(float4*)(out + (size_t)n * 384 + 128 + (size_t)t * 128 + j0) = r;
    }
}

extern "C" void kernel_launch(void* const* d_in, const int* in_sizes, int n_in,
                              void* d_out, int out_size, void* d_ws, size_t ws_size,
                              hipStream_t stream)
{
    const float* x  = (const float*)d_in[0];
    const float* wu = (const float*)d_in[1];
    const float* bu = (const float*)d_in[2];
    const float* wv = (const float*)d_in[3];
    const int* s0 = (const int*)d_in[4];
    const int* d0 = (const int*)d_in[5];
    const int* s1 = (const int*)d_in[6];
    const int* d1 = (const int*)d_in[7];
    float* out = (float*)d_out;
    int N = in_sizes[0] / 128;
    int E = in_sizes[4];

    int nr = ((N - 1) >> RSHIFT) + 1;               // 25 for N=50000 (<= MAXR)
    long long mean = (long long)RW * E / N;         // ~32768
    int cap = (int)(mean + mean / 4 + 2048);        // ~43K (>40 sigma margin)

    char* ws = (char*)d_ws;
    size_t o = 0;
    auto alloc = [&](size_t bytes) -> void* {
        void* p = ws + o;
        o = (o + bytes + 255) & ~(size_t)255;
        return p;
    };
    float* su       = (float*)alloc((size_t)N * 16 * 4);
    float* sv       = (float*)alloc((size_t)N * 16 * 4);
    int* gcur       = (int*)alloc((size_t)2 * MAXR * 4);
    int* off        = (int*)alloc((size_t)2 * (N + 1) * 4);
    unsigned* pairs = (unsigned*)alloc((size_t)2 * nr * cap * 4);
    ushort* bucket  = (ushort*)alloc((size_t)2 * E * 2);
    ushort* xbf     = (ushort*)alloc((size_t)N * 128 * 2);

    int convBlocks  = (N * 32 + 255) / 256;
    int scoreBlocks = (N + 15) / 16;
    int ppset       = (E + CHUNKP - 1) / CHUNKP;

    hipMemsetAsync(gcur, 0, (size_t)2 * MAXR * 4, stream);
    mega_kernel<<<convBlocks + scoreBlocks + 2 * ppset, 256, 0, stream>>>(
        x, wu, bu, wv, s0, d0, s1, d1, out, xbf, su, sv,
        gcur, pairs, N, E, nr, cap, convBlocks, scoreBlocks, ppset);
    build_kernel<<<dim3(nr, 2), 1024, 0, stream>>>(
        pairs, gcur, off, bucket, N, E, nr, cap);
    agg_kernel<<<dim3((N + 3) / 4, 2), 256, 0, stream>>>(
        xbf, su, sv, off, bucket, out, N, E);
}